// Round 9
// baseline (403.625 us; speedup 1.0000x reference)
//
#include <hip/hip_runtime.h>

#define NCL 20000
#define DIN 128
#define HID 2048
#define SEVN 2000
#define TPM 0.1f
#define ENTC 0.01f

// workspace byte offsets (all 256-aligned)
#define WS_B2K   0
#define WS_W2K   256                 // 8 KB -> 8448
#define WS_LOGIT 8448                // 20000*4 = 80000 -> 88448
#define WS_CDATA 89600               // 20000*16 = 320000 -> 409600
#define WS_BSTG  409600              // 128*2048*2 = 524288 -> 933888

#define NB_SB   128
#define NB_WK   513

typedef __attribute__((ext_vector_type(8))) short short8;
typedef __attribute__((ext_vector_type(4))) float f32x4;

static __device__ __forceinline__ unsigned short f2bf(float f) {
    unsigned u = __float_as_uint(f);
    u += 0x7FFFu + ((u >> 16) & 1u);     // round-to-nearest-even
    return (unsigned short)(u >> 16);
}
static __device__ __forceinline__ unsigned pck(unsigned short a, unsigned short b) {
    return (unsigned)a | ((unsigned)b << 16);
}

// ---------- K1: small streamer: stageB (W1 -> bf16 B-frag) + w2k ----------
__global__ __launch_bounds__(256) void k_stream(const float* __restrict__ W1,
                                                unsigned short* __restrict__ bst,
                                                const float* __restrict__ W2,
                                                const float* __restrict__ b2,
                                                const float* __restrict__ key,
                                                float* __restrict__ w2k,
                                                float* __restrict__ b2k) {
    int b = blockIdx.x;
    int t = threadIdx.x;

    if (b < NB_SB) {
        // ---- stage W1 -> bf16 B-frag: layout [ct=128][c=4][lane=64][j=8] ----
        int g = b * 256 + t;
        int l = g & 63, c = (g >> 6) & 3, ct = g >> 8;
        int col = ct * 16 + (l & 15);
        int kb  = c * 32 + (l >> 4) * 8;
        unsigned short v[8];
        #pragma unroll
        for (int j = 0; j < 8; ++j) v[j] = f2bf(W1[(size_t)(kb + j) * HID + col]);
        uint4 o;
        o.x = pck(v[0], v[1]); o.y = pck(v[2], v[3]);
        o.z = pck(v[4], v[5]); o.w = pck(v[6], v[7]);
        ((uint4*)bst)[g] = o;
        return;
    }
    b -= NB_SB;

    // ---- w2k = W2 @ key; b2k = b2 . key ----
    {
        int wid  = b * 4 + (t >> 6);
        int lane = t & 63;
        const float4* key4 = (const float4*)key;
        float acc = 0.f;
        if (wid <= HID) {
            const float4* row4 = (const float4*)((wid < HID) ? (W2 + (size_t)wid * 2048) : b2);
            #pragma unroll
            for (int it = 0; it < 8; ++it) {
                int idx = it * 64 + lane;
                float4 a = row4[idx], k4 = key4[idx];
                acc += a.x * k4.x + a.y * k4.y + a.z * k4.z + a.w * k4.w;
            }
        }
        #pragma unroll
        for (int m = 1; m < 64; m <<= 1) acc += __shfl_xor(acc, m);
        if (lane == 0 && wid < HID) w2k[wid] = acc;
        if (lane == 0 && wid == HID) *b2k = acc;
    }
}

// ---------- K2: logits = relu(fv@W1+b1)@w2k + b2k; fv loaded direct; fused clause epi ----------
// 625 blocks x 256 thr (4 waves). Block owns 32 rows; wave w owns ct in [w*32, w*32+32).
__global__ __launch_bounds__(256) void k_gemm(const float* __restrict__ fv,
                                              const unsigned short* __restrict__ bst,
                                              const float* __restrict__ b1,
                                              const float* __restrict__ w2k,
                                              const float* __restrict__ b2k,
                                              const int* __restrict__ good,
                                              float* __restrict__ logits,
                                              float4* __restrict__ cd) {
    int blk = blockIdx.x;
    int tid = threadIdx.x;
    int w = tid >> 6, l = tid & 63;
    int colg = l & 15, kg = l >> 4;
    int r0 = blk * 32;

    const short8* B8 = (const short8*)bst;

    short8 afrag[2][4];
    #pragma unroll
    for (int s = 0; s < 2; ++s) {
        const float* rp = fv + (size_t)(r0 + s * 16 + (l & 15)) * DIN + kg * 8;
        #pragma unroll
        for (int c = 0; c < 4; ++c) {
            float4 f0 = *(const float4*)(rp + c * 32);
            float4 f1 = *(const float4*)(rp + c * 32 + 4);
            union { short8 sv; uint4 u; } tmp;
            tmp.u.x = pck(f2bf(f0.x), f2bf(f0.y));
            tmp.u.y = pck(f2bf(f0.z), f2bf(f0.w));
            tmp.u.z = pck(f2bf(f1.x), f2bf(f1.y));
            tmp.u.w = pck(f2bf(f1.z), f2bf(f1.w));
            afrag[s][c] = tmp.sv;
        }
    }

    float acc[2][4];
    #pragma unroll
    for (int s = 0; s < 2; ++s)
        #pragma unroll
        for (int r = 0; r < 4; ++r) acc[s][r] = 0.f;

    int ct0 = w * 32;
    for (int t = 0; t < 32; ++t) {
        int ct = ct0 + t;
        short8 bfr[4];
        #pragma unroll
        for (int c = 0; c < 4; ++c) bfr[c] = B8[((ct * 4 + c) << 6) + l];
        int col = ct * 16 + colg;
        float b1v = b1[col];
        float wkv = w2k[col];
        #pragma unroll
        for (int s = 0; s < 2; ++s) {
            f32x4 d = {0.f, 0.f, 0.f, 0.f};
            #pragma unroll
            for (int c = 0; c < 4; ++c)
                d = __builtin_amdgcn_mfma_f32_16x16x32_bf16(afrag[s][c], bfr[c], d, 0, 0, 0);
            #pragma unroll
            for (int r = 0; r < 4; ++r) {
                float h = d[r] + b1v;
                h = h > 0.f ? h : 0.f;
                acc[s][r] += h * wkv;
            }
        }
    }

    __shared__ float red[4][32];
    #pragma unroll
    for (int s = 0; s < 2; ++s) {
        #pragma unroll
        for (int r = 0; r < 4; ++r) {
            float a = acc[s][r];
            a += __shfl_xor(a, 1);
            a += __shfl_xor(a, 2);
            a += __shfl_xor(a, 4);
            a += __shfl_xor(a, 8);
            if (colg == 0) red[w][s * 16 + kg * 4 + r] = a;
        }
    }
    __syncthreads();
    if (tid < 32) {
        float sum = *b2k;
        #pragma unroll
        for (int ww = 0; ww < 4; ++ww) sum += red[ww][tid];
        int row = r0 + tid;
        logits[row] = sum;
        float e = expf(sum);                 // logits O(+-6): fp32 exp safe
        bool g = good[row] != 0;
        cd[row] = make_float4(e, e * sum, g ? sum : 0.f, g ? 1.f : 0.f);
    }
}

// ---------- K3: fused events — block = event; lane t owns clauses {t, t+256, ...} ----------
// mask: 1 dword/lane/iter (256 B/wave, minimal). cd: 1 float4/lane/iter at 16-B lane
// stride (16 lines/instr, minimal). 5 branchless fmas per clause.
__global__ __launch_bounds__(256) void k_events(const unsigned* __restrict__ mask,
                                                const float4* __restrict__ cd,
                                                const float* __restrict__ logits,
                                                const float* __restrict__ times,
                                                const int* __restrict__ sel,
                                                float* __restrict__ out) {
    int s = blockIdx.x;
    int t = threadIdx.x;
    const unsigned* mrow = mask + (size_t)s * NCL;
    float Z = 0.f, X = 0.f, cnt = 0.f, ng = 0.f, sg = 0.f;

    // 78 full strides: max index = 255 + 77*256 = 19967 < 20000
    #pragma unroll 4
    for (int k = 0; k < 78; ++k) {
        int i = k * 256 + t;
        unsigned m = mrow[i];
        float4 c = cd[i];
        float mm = (m != 0u) ? 1.f : 0.f;
        Z   += mm * c.x;
        X   += mm * c.y;
        sg  += mm * c.z;
        ng  += mm * c.w;
        cnt += mm;
    }
    // tail: clauses 19968..19999
    if (t < 32) {
        int i = 19968 + t;
        unsigned m = mrow[i];
        float4 c = cd[i];
        float mm = (m != 0u) ? 1.f : 0.f;
        Z   += mm * c.x;
        X   += mm * c.y;
        sg  += mm * c.z;
        ng  += mm * c.w;
        cnt += mm;
    }

    #pragma unroll
    for (int m = 1; m < 64; m <<= 1) {
        Z   += __shfl_xor(Z, m);
        X   += __shfl_xor(X, m);
        cnt += __shfl_xor(cnt, m);
        ng  += __shfl_xor(ng, m);
        sg  += __shfl_xor(sg, m);
    }
    __shared__ float red[4][5];
    int lane = t & 63, w = t >> 6;
    if (lane == 0) {
        red[w][0] = Z; red[w][1] = X; red[w][2] = cnt; red[w][3] = ng; red[w][4] = sg;
    }
    __syncthreads();
    if (t == 0) {
        Z   = red[0][0] + red[1][0] + red[2][0] + red[3][0];
        X   = red[0][1] + red[1][1] + red[2][1] + red[3][1];
        cnt = red[0][2] + red[1][2] + red[2][2] + red[3][2];
        ng  = red[0][3] + red[1][3] + red[2][3] + red[3][3];
        sg  = red[0][4] + red[1][4] + red[2][4] + red[3][4];
        float L = logf(Z);
        if (ng > 0.5f) {
            atomicAdd(out + 0, L - sg / ng);
            atomicAdd(out + 1, 1.f);
        }
        float tm = times[s];
        atomicAdd(out + 2, TPM * tm * (logits[sel[s]] - L));
        atomicAdd(out + 3, tm);
        atomicAdd(out + 4, ENTC * ((X / Z - L) / logf(cnt)));
        if (s == 0) out[5] = (float)SEVN;
    }
}

extern "C" void kernel_launch(void* const* d_in, const int* in_sizes, int n_in,
                              void* d_out, int out_size, void* d_ws, size_t ws_size,
                              hipStream_t stream) {
    const float* fv    = (const float*)d_in[0];
    const float* W1    = (const float*)d_in[1];
    const float* b1    = (const float*)d_in[2];
    const float* W2    = (const float*)d_in[3];
    const float* b2    = (const float*)d_in[4];
    const float* key   = (const float*)d_in[5];
    const float* times = (const float*)d_in[6];
    const unsigned* mask = (const unsigned*)d_in[7];   // bool -> int32
    const int* good    = (const int*)d_in[8];          // bool -> int32
    const int* sel     = (const int*)d_in[9];
    float* out = (float*)d_out;
    char* ws = (char*)d_ws;

    float* w2k    = (float*)(ws + WS_W2K);
    float* b2k    = (float*)(ws + WS_B2K);
    float* logits = (float*)(ws + WS_LOGIT);
    float4* cdata = (float4*)(ws + WS_CDATA);
    unsigned short* bst = (unsigned short*)(ws + WS_BSTG);

    hipMemsetAsync(d_out, 0, 6 * sizeof(float), stream);
    k_stream<<<NB_SB + NB_WK, 256, 0, stream>>>(W1, bst, W2, b2, key, w2k, b2k);
    k_gemm <<<NCL / 32, 256, 0, stream>>>(fv, bst, b1, w2k, b2k, good, logits, cdata);
    k_events<<<SEVN, 256, 0, stream>>>(mask, cdata, logits, times, sel, out);
}

// Round 10
// 303.566 us; speedup vs baseline: 1.3296x; 1.3296x over previous
//
#include <hip/hip_runtime.h>

#define NCL 20000
#define DIN 128
#define HID 2048
#define SEVN 2000
#define TPM 0.1f
#define ENTC 0.01f

#define HHALF 10000         // clauses per staged half
#define EPB 8               // events per block (amortize LDS staging)
#define SPAD 2048

// workspace byte offsets (16/256-aligned)
#define WS_B2K   0
#define WS_W2K   256                  // 8192 -> 8448
#define WS_LOGIT 8448                 // 80000 -> 88448
#define WS_EARR  88576                // 80000 -> 168576
#define WS_LBF   168704               // 40000 -> 208704
#define WS_GBW   208896               // 2560  -> 211456
#define WS_PART  211712               // 8*5*2048*4 = 327680 -> 539392
#define WS_BSTG  539648               // 524288 -> 1063936

#define NB_SB 128
#define NB_WK 513
#define NB_GB 3

typedef __attribute__((ext_vector_type(8))) short short8;
typedef __attribute__((ext_vector_type(4))) float f32x4;

static __device__ __forceinline__ unsigned short f2bf(float f) {
    unsigned u = __float_as_uint(f);
    u += 0x7FFFu + ((u >> 16) & 1u);     // round-to-nearest-even
    return (unsigned short)(u >> 16);
}
static __device__ __forceinline__ unsigned pck(unsigned short a, unsigned short b) {
    return (unsigned)a | ((unsigned)b << 16);
}

// ---------- K1: stageB (W1 -> bf16 B-frag) + w2k + good-bit pack ----------
__global__ __launch_bounds__(256) void k_stream(const float* __restrict__ W1,
                                                unsigned short* __restrict__ bst,
                                                const float* __restrict__ W2,
                                                const float* __restrict__ b2,
                                                const float* __restrict__ key,
                                                const int* __restrict__ good,
                                                float* __restrict__ w2k,
                                                float* __restrict__ b2k,
                                                unsigned* __restrict__ gbw) {
    int b = blockIdx.x;
    int t = threadIdx.x;

    if (b < NB_SB) {
        // ---- stage W1 -> bf16 B-frag: layout [ct=128][c=4][lane=64][j=8] ----
        int g = b * 256 + t;
        int l = g & 63, c = (g >> 6) & 3, ct = g >> 8;
        int col = ct * 16 + (l & 15);
        int kb  = c * 32 + (l >> 4) * 8;
        unsigned short v[8];
        #pragma unroll
        for (int j = 0; j < 8; ++j) v[j] = f2bf(W1[(size_t)(kb + j) * HID + col]);
        uint4 o;
        o.x = pck(v[0], v[1]); o.y = pck(v[2], v[3]);
        o.z = pck(v[4], v[5]); o.w = pck(v[6], v[7]);
        ((uint4*)bst)[g] = o;
        return;
    }
    b -= NB_SB;

    if (b < NB_WK) {
        // ---- w2k = W2 @ key; b2k = b2 . key ----
        int wid  = b * 4 + (t >> 6);
        int lane = t & 63;
        const float4* key4 = (const float4*)key;
        float acc = 0.f;
        if (wid <= HID) {
            const float4* row4 = (const float4*)((wid < HID) ? (W2 + (size_t)wid * 2048) : b2);
            #pragma unroll
            for (int it = 0; it < 8; ++it) {
                int idx = it * 64 + lane;
                float4 a = row4[idx], k4 = key4[idx];
                acc += a.x * k4.x + a.y * k4.y + a.z * k4.z + a.w * k4.w;
            }
        }
        #pragma unroll
        for (int m = 1; m < 64; m <<= 1) acc += __shfl_xor(acc, m);
        if (lane == 0 && wid < HID) w2k[wid] = acc;
        if (lane == 0 && wid == HID) *b2k = acc;
        return;
    }
    b -= NB_WK;

    // ---- good-bit pack: per half h, word w covers clauses h*HHALF+32w.. ----
    {
        int id = b * 256 + t;           // 0..767
        if (id < 626) {
            int h = id / 313, w = id - h * 313;
            int base = h * HHALF + 32 * w;
            int nb = (w == 312) ? 16 : 32;
            unsigned wordv = 0;
            for (int j = 0; j < nb; ++j)
                wordv |= (good[base + j] != 0 ? 1u : 0u) << j;
            gbw[h * 320 + w] = wordv;
        }
    }
}

// ---------- K2: logits = relu(fv@W1+b1)@w2k + b2k; writes logits + E + bf16 L ----------
// 625 blocks x 256 thr (4 waves). Block owns 32 rows; wave w owns ct in [w*32, w*32+32).
__global__ __launch_bounds__(256) void k_gemm(const float* __restrict__ fv,
                                              const unsigned short* __restrict__ bst,
                                              const float* __restrict__ b1,
                                              const float* __restrict__ w2k,
                                              const float* __restrict__ b2k,
                                              float* __restrict__ logits,
                                              float* __restrict__ Earr,
                                              unsigned short* __restrict__ Lbf) {
    int blk = blockIdx.x;
    int tid = threadIdx.x;
    int w = tid >> 6, l = tid & 63;
    int colg = l & 15, kg = l >> 4;
    int r0 = blk * 32;

    const short8* B8 = (const short8*)bst;

    short8 afrag[2][4];
    #pragma unroll
    for (int s = 0; s < 2; ++s) {
        const float* rp = fv + (size_t)(r0 + s * 16 + (l & 15)) * DIN + kg * 8;
        #pragma unroll
        for (int c = 0; c < 4; ++c) {
            float4 f0 = *(const float4*)(rp + c * 32);
            float4 f1 = *(const float4*)(rp + c * 32 + 4);
            union { short8 sv; uint4 u; } tmp;
            tmp.u.x = pck(f2bf(f0.x), f2bf(f0.y));
            tmp.u.y = pck(f2bf(f0.z), f2bf(f0.w));
            tmp.u.z = pck(f2bf(f1.x), f2bf(f1.y));
            tmp.u.w = pck(f2bf(f1.z), f2bf(f1.w));
            afrag[s][c] = tmp.sv;
        }
    }

    float acc[2][4];
    #pragma unroll
    for (int s = 0; s < 2; ++s)
        #pragma unroll
        for (int r = 0; r < 4; ++r) acc[s][r] = 0.f;

    int ct0 = w * 32;
    for (int t = 0; t < 32; ++t) {
        int ct = ct0 + t;
        short8 bfr[4];
        #pragma unroll
        for (int c = 0; c < 4; ++c) bfr[c] = B8[((ct * 4 + c) << 6) + l];
        int col = ct * 16 + colg;
        float b1v = b1[col];
        float wkv = w2k[col];
        #pragma unroll
        for (int s = 0; s < 2; ++s) {
            f32x4 d = {0.f, 0.f, 0.f, 0.f};
            #pragma unroll
            for (int c = 0; c < 4; ++c)
                d = __builtin_amdgcn_mfma_f32_16x16x32_bf16(afrag[s][c], bfr[c], d, 0, 0, 0);
            #pragma unroll
            for (int r = 0; r < 4; ++r) {
                float h = d[r] + b1v;
                h = h > 0.f ? h : 0.f;
                acc[s][r] += h * wkv;
            }
        }
    }

    __shared__ float red[4][32];
    #pragma unroll
    for (int s = 0; s < 2; ++s) {
        #pragma unroll
        for (int r = 0; r < 4; ++r) {
            float a = acc[s][r];
            a += __shfl_xor(a, 1);
            a += __shfl_xor(a, 2);
            a += __shfl_xor(a, 4);
            a += __shfl_xor(a, 8);
            if (colg == 0) red[w][s * 16 + kg * 4 + r] = a;
        }
    }
    __syncthreads();
    if (tid < 32) {
        float sum = *b2k;
        #pragma unroll
        for (int ww = 0; ww < 4; ++ww) sum += red[ww][tid];
        int row = r0 + tid;
        logits[row] = sum;
        Earr[row] = expf(sum);           // logits O(+-6): fp32 exp safe
        Lbf[row]  = f2bf(sum);
    }
}

// ---------- K3: events — LDS-staged clause table, mask-only stream ----------
// block = (half h, event-group of 8). Stage E(fp32)+L(bf16)+goodbits for the half,
// then per event stream mask dwords (batch 13 in flight), all clause data from LDS.
__global__ __launch_bounds__(256) void k_events(const unsigned* __restrict__ mask,
                                                const float* __restrict__ Earr,
                                                const unsigned short* __restrict__ Lbf,
                                                const unsigned* __restrict__ gbw,
                                                float* __restrict__ part) {
    __shared__ float Es[HHALF];            // 40000 B
    __shared__ unsigned short Ls[HHALF];   // 20000 B
    __shared__ unsigned Gs[313];           // 1252 B
    int blk = blockIdx.x;
    int h  = blk & 1;
    int eg = blk >> 1;                     // 0..249
    int t = threadIdx.x;

    // ---- stage ----
    {
        const float4* Eg4 = (const float4*)(Earr + h * HHALF);
        float4* Es4 = (float4*)Es;
        #pragma unroll
        for (int j = 0; j < 10; ++j) {
            int idx = j * 256 + t;
            if (idx < 2500) Es4[idx] = Eg4[idx];
        }
        const uint4* Lg4 = (const uint4*)(Lbf + h * HHALF);
        uint4* Ls4 = (uint4*)Ls;
        #pragma unroll
        for (int j = 0; j < 5; ++j) {
            int idx = j * 256 + t;
            if (idx < 1250) Ls4[idx] = Lg4[idx];
        }
        if (t < 313) Gs[t] = gbw[h * 320 + t];
        int t2 = t + 256;
        if (t2 < 313) Gs[t2] = gbw[h * 320 + t2];
    }
    __syncthreads();

    int wv = t >> 6, lane = t & 63;
    int shiftbit = t & 31;
    float* pc = part + (size_t)(h * 4 + wv) * 5 * SPAD;

    for (int e = 0; e < EPB; ++e) {
        int s = eg * EPB + e;
        const unsigned* mrow = mask + (size_t)s * NCL + h * HHALF;
        float Z = 0.f, X = 0.f, cnt = 0.f, ng = 0.f, sg = 0.f;
        // 39 full strides = 3 batches of 13 (covers 9984)
        for (int kb = 0; kb < 3; ++kb) {
            unsigned mv[13];
            #pragma unroll
            for (int j = 0; j < 13; ++j)
                mv[j] = mrow[(kb * 13 + j) * 256 + t];
            #pragma unroll
            for (int j = 0; j < 13; ++j) {
                int i = (kb * 13 + j) * 256 + t;
                float E = Es[i];
                float l = __uint_as_float(((unsigned)Ls[i]) << 16);
                unsigned gw = Gs[i >> 5];
                bool m = mv[j] != 0u;
                bool g = ((gw >> shiftbit) & 1u) != 0u;
                float me = m ? E : 0.f;
                Z += me;
                X = fmaf(me, l, X);
                cnt += m ? 1.f : 0.f;
                sg += (m && g) ? l : 0.f;
                ng += (m && g) ? 1.f : 0.f;
            }
        }
        // tail clauses 9984..9999
        if (t < 16) {
            int i = 9984 + t;
            unsigned mvt = mrow[i];
            float E = Es[i];
            float l = __uint_as_float(((unsigned)Ls[i]) << 16);
            unsigned gw = Gs[i >> 5];
            bool m = mvt != 0u;
            bool g = ((gw >> (i & 31)) & 1u) != 0u;
            float me = m ? E : 0.f;
            Z += me;
            X = fmaf(me, l, X);
            cnt += m ? 1.f : 0.f;
            sg += (m && g) ? l : 0.f;
            ng += (m && g) ? 1.f : 0.f;
        }
        #pragma unroll
        for (int m = 1; m < 64; m <<= 1) {
            Z   += __shfl_xor(Z, m);
            X   += __shfl_xor(X, m);
            cnt += __shfl_xor(cnt, m);
            ng  += __shfl_xor(ng, m);
            sg  += __shfl_xor(sg, m);
        }
        if (lane == 0) {
            pc[0 * SPAD + s] = Z;
            pc[1 * SPAD + s] = X;
            pc[2 * SPAD + s] = cnt;
            pc[3 * SPAD + s] = ng;
            pc[4 * SPAD + s] = sg;
        }
    }
}

// ---------- K4: final reduction (8 chunks) + epilogue ----------
__global__ __launch_bounds__(256) void k_final(const float* __restrict__ part,
                                               const float* __restrict__ logits,
                                               const float* __restrict__ times,
                                               const int* __restrict__ sel,
                                               float* __restrict__ out) {
    int s = blockIdx.x * 256 + threadIdx.x;  // 0..2047
    bool live = s < SEVN;
    float Z = 0.f, X = 0.f, cnt = 0.f, ng = 0.f, sg = 0.f;
    if (live) {
        #pragma unroll
        for (int c = 0; c < 8; ++c) {
            const float* pp = part + (size_t)c * 5 * SPAD;
            Z   += pp[0 * SPAD + s];
            X   += pp[1 * SPAD + s];
            cnt += pp[2 * SPAD + s];
            ng  += pp[3 * SPAD + s];
            sg  += pp[4 * SPAD + s];
        }
    }
    float gl = 0.f, ngs = 0.f, tl = 0.f, tv = 0.f, en = 0.f;
    if (live) {
        float L = logf(Z);
        if (ng > 0.5f) { gl = L - sg / ng; ngs = 1.f; }
        float tm = times[s];
        tl = TPM * tm * (logits[sel[s]] - L);
        tv = tm;
        en = ENTC * ((X / Z - L) / logf(cnt));
    }
    #pragma unroll
    for (int m = 1; m < 64; m <<= 1) {
        gl  += __shfl_xor(gl, m);
        ngs += __shfl_xor(ngs, m);
        tl  += __shfl_xor(tl, m);
        tv  += __shfl_xor(tv, m);
        en  += __shfl_xor(en, m);
    }
    if ((threadIdx.x & 63) == 0) {
        atomicAdd(out + 0, gl);
        atomicAdd(out + 1, ngs);
        atomicAdd(out + 2, tl);
        atomicAdd(out + 3, tv);
        atomicAdd(out + 4, en);
    }
    if (s == 0) out[5] = (float)SEVN;
}

extern "C" void kernel_launch(void* const* d_in, const int* in_sizes, int n_in,
                              void* d_out, int out_size, void* d_ws, size_t ws_size,
                              hipStream_t stream) {
    const float* fv    = (const float*)d_in[0];
    const float* W1    = (const float*)d_in[1];
    const float* b1    = (const float*)d_in[2];
    const float* W2    = (const float*)d_in[3];
    const float* b2    = (const float*)d_in[4];
    const float* key   = (const float*)d_in[5];
    const float* times = (const float*)d_in[6];
    const unsigned* mask = (const unsigned*)d_in[7];   // bool -> int32
    const int* good    = (const int*)d_in[8];          // bool -> int32
    const int* sel     = (const int*)d_in[9];
    float* out = (float*)d_out;
    char* ws = (char*)d_ws;

    float* w2k    = (float*)(ws + WS_W2K);
    float* b2k    = (float*)(ws + WS_B2K);
    float* logits = (float*)(ws + WS_LOGIT);
    float* Earr   = (float*)(ws + WS_EARR);
    unsigned short* Lbf = (unsigned short*)(ws + WS_LBF);
    unsigned* gbw = (unsigned*)(ws + WS_GBW);
    float* part   = (float*)(ws + WS_PART);
    unsigned short* bst = (unsigned short*)(ws + WS_BSTG);

    hipMemsetAsync(d_out, 0, 6 * sizeof(float), stream);
    k_stream<<<NB_SB + NB_WK + NB_GB, 256, 0, stream>>>(W1, bst, W2, b2, key, good,
                                                        w2k, b2k, gbw);
    k_gemm <<<NCL / 32, 256, 0, stream>>>(fv, bst, b1, w2k, b2k, logits, Earr, Lbf);
    k_events<<<500, 256, 0, stream>>>(mask, Earr, Lbf, gbw, part);
    k_final<<<SPAD / 256, 256, 0, stream>>>(part, logits, times, sel, out);
}

// Round 11
// 300.704 us; speedup vs baseline: 1.3423x; 1.0095x over previous
//
#include <hip/hip_runtime.h>

#define NCL 20000
#define DIN 128
#define HID 2048
#define SEVN 2000
#define TPM 0.1f
#define ENTC 0.01f

#define HHALF 10000         // clauses per staged half
#define EPB 8               // events per block
#define SPAD 2048

// workspace byte offsets (16/256-aligned)
#define WS_B2K   0
#define WS_W2K   256                  // 8192  -> 8448
#define WS_LOGIT 8448                 // 80000 -> 88448
#define WS_ELPK  88576                // 80000 -> 168576
#define WS_PART  168704               // 8*5*2048*4 = 327680 -> 496384
#define WS_BSTG  496640               // 524288 -> 1020928
#define WS_GBW   1021184              // 2560 -> 1023744

#define NB_SB 128
#define NB_WK 513
#define NB_GB 3

typedef __attribute__((ext_vector_type(8))) short short8;
typedef __attribute__((ext_vector_type(4))) float f32x4;

static __device__ __forceinline__ unsigned short f2bf(float f) {
    unsigned u = __float_as_uint(f);
    u += 0x7FFFu + ((u >> 16) & 1u);     // round-to-nearest-even
    return (unsigned short)(u >> 16);
}
static __device__ __forceinline__ unsigned pck(unsigned short a, unsigned short b) {
    return (unsigned)a | ((unsigned)b << 16);
}

// ---------- K1: stageB (W1 -> bf16 B-frag) + w2k + good-bit pack ----------
__global__ __launch_bounds__(256) void k_stream(const float* __restrict__ W1,
                                                unsigned short* __restrict__ bst,
                                                const float* __restrict__ W2,
                                                const float* __restrict__ b2,
                                                const float* __restrict__ key,
                                                const int* __restrict__ good,
                                                float* __restrict__ w2k,
                                                float* __restrict__ b2k,
                                                unsigned* __restrict__ gbw) {
    int b = blockIdx.x;
    int t = threadIdx.x;

    if (b < NB_SB) {
        // ---- stage W1 -> bf16 B-frag: layout [ct=128][c=4][lane=64][j=8] ----
        int g = b * 256 + t;
        int l = g & 63, c = (g >> 6) & 3, ct = g >> 8;
        int col = ct * 16 + (l & 15);
        int kb  = c * 32 + (l >> 4) * 8;
        unsigned short v[8];
        #pragma unroll
        for (int j = 0; j < 8; ++j) v[j] = f2bf(W1[(size_t)(kb + j) * HID + col]);
        uint4 o;
        o.x = pck(v[0], v[1]); o.y = pck(v[2], v[3]);
        o.z = pck(v[4], v[5]); o.w = pck(v[6], v[7]);
        ((uint4*)bst)[g] = o;
        return;
    }
    b -= NB_SB;

    if (b < NB_WK) {
        // ---- w2k = W2 @ key; b2k = b2 . key ----
        int wid  = b * 4 + (t >> 6);
        int lane = t & 63;
        const float4* key4 = (const float4*)key;
        float acc = 0.f;
        if (wid <= HID) {
            const float4* row4 = (const float4*)((wid < HID) ? (W2 + (size_t)wid * 2048) : b2);
            #pragma unroll
            for (int it = 0; it < 8; ++it) {
                int idx = it * 64 + lane;
                float4 a = row4[idx], k4 = key4[idx];
                acc += a.x * k4.x + a.y * k4.y + a.z * k4.z + a.w * k4.w;
            }
        }
        #pragma unroll
        for (int m = 1; m < 64; m <<= 1) acc += __shfl_xor(acc, m);
        if (lane == 0 && wid < HID) w2k[wid] = acc;
        if (lane == 0 && wid == HID) *b2k = acc;
        return;
    }
    b -= NB_WK;

    // ---- good-bit pack: per half h, word w covers clauses h*HHALF + 32w.. ----
    {
        int id = b * 256 + t;           // 0..767
        if (id < 626) {
            int h = id / 313, w = id - h * 313;
            int base = h * HHALF + 32 * w;
            int nb = (w == 312) ? 16 : 32;
            unsigned wordv = 0;
            for (int j = 0; j < nb; ++j)
                wordv |= (good[base + j] != 0 ? 1u : 0u) << j;
            gbw[h * 320 + w] = wordv;
        }
    }
}

// ---------- K2: logits = relu(fv@W1+b1)@w2k + b2k; writes logits + packed {E,L} ----------
// 625 blocks x 256 thr (4 waves). Block owns 32 rows; wave w owns ct in [w*32, w*32+32).
__global__ __launch_bounds__(256) void k_gemm(const float* __restrict__ fv,
                                              const unsigned short* __restrict__ bst,
                                              const float* __restrict__ b1,
                                              const float* __restrict__ w2k,
                                              const float* __restrict__ b2k,
                                              float* __restrict__ logits,
                                              unsigned* __restrict__ ELpk) {
    int blk = blockIdx.x;
    int tid = threadIdx.x;
    int w = tid >> 6, l = tid & 63;
    int colg = l & 15, kg = l >> 4;
    int r0 = blk * 32;

    const short8* B8 = (const short8*)bst;

    short8 afrag[2][4];
    #pragma unroll
    for (int s = 0; s < 2; ++s) {
        const float* rp = fv + (size_t)(r0 + s * 16 + (l & 15)) * DIN + kg * 8;
        #pragma unroll
        for (int c = 0; c < 4; ++c) {
            float4 f0 = *(const float4*)(rp + c * 32);
            float4 f1 = *(const float4*)(rp + c * 32 + 4);
            union { short8 sv; uint4 u; } tmp;
            tmp.u.x = pck(f2bf(f0.x), f2bf(f0.y));
            tmp.u.y = pck(f2bf(f0.z), f2bf(f0.w));
            tmp.u.z = pck(f2bf(f1.x), f2bf(f1.y));
            tmp.u.w = pck(f2bf(f1.z), f2bf(f1.w));
            afrag[s][c] = tmp.sv;
        }
    }

    float acc[2][4];
    #pragma unroll
    for (int s = 0; s < 2; ++s)
        #pragma unroll
        for (int r = 0; r < 4; ++r) acc[s][r] = 0.f;

    int ct0 = w * 32;
    for (int t = 0; t < 32; ++t) {
        int ct = ct0 + t;
        short8 bfr[4];
        #pragma unroll
        for (int c = 0; c < 4; ++c) bfr[c] = B8[((ct * 4 + c) << 6) + l];
        int col = ct * 16 + colg;
        float b1v = b1[col];
        float wkv = w2k[col];
        #pragma unroll
        for (int s = 0; s < 2; ++s) {
            f32x4 d = {0.f, 0.f, 0.f, 0.f};
            #pragma unroll
            for (int c = 0; c < 4; ++c)
                d = __builtin_amdgcn_mfma_f32_16x16x32_bf16(afrag[s][c], bfr[c], d, 0, 0, 0);
            #pragma unroll
            for (int r = 0; r < 4; ++r) {
                float h = d[r] + b1v;
                h = h > 0.f ? h : 0.f;
                acc[s][r] += h * wkv;
            }
        }
    }

    __shared__ float red[4][32];
    #pragma unroll
    for (int s = 0; s < 2; ++s) {
        #pragma unroll
        for (int r = 0; r < 4; ++r) {
            float a = acc[s][r];
            a += __shfl_xor(a, 1);
            a += __shfl_xor(a, 2);
            a += __shfl_xor(a, 4);
            a += __shfl_xor(a, 8);
            if (colg == 0) red[w][s * 16 + kg * 4 + r] = a;
        }
    }
    __syncthreads();
    if (tid < 32) {
        float sum = *b2k;
        #pragma unroll
        for (int ww = 0; ww < 4; ++ww) sum += red[ww][tid];
        int row = r0 + tid;
        logits[row] = sum;
        float e = expf(sum);                 // logits O(+-6): fp32 exp safe
        ELpk[row] = ((unsigned)f2bf(e) << 16) | (unsigned)f2bf(sum);
    }
}

// ---------- K3: events — 40KB packed LDS table, reg good-bitmap, mask-only stream ----------
// block = (half h, event-group of 8). decode: E = w & 0xFFFF0000, L = w << 16.
__global__ __launch_bounds__(256) void k_events(const unsigned* __restrict__ mask,
                                                const unsigned* __restrict__ ELpk,
                                                const unsigned* __restrict__ gbw,
                                                float* __restrict__ part) {
    __shared__ unsigned ELs[HHALF];        // 40000 B -> 4 blocks/CU
    int blk = blockIdx.x;
    int h  = blk & 1;
    int eg = blk >> 1;                     // 0..249
    int t = threadIdx.x;

    // ---- stage packed table ----
    {
        const uint4* Eg4 = (const uint4*)(ELpk + h * HHALF);
        uint4* Es4 = (uint4*)ELs;
        #pragma unroll
        for (int j = 0; j < 10; ++j) {
            int idx = j * 256 + t;
            if (idx < 2500) Es4[idx] = Eg4[idx];
        }
    }
    // ---- per-thread good bitmap: bit k = good[h*HHALF + k*256 + t] ----
    unsigned long long gbm = 0;
    {
        const unsigned* gb = gbw + h * 320;
        int sb = t & 31;
        #pragma unroll
        for (int k = 0; k < 39; ++k)
            gbm |= (unsigned long long)((gb[k * 8 + (t >> 5)] >> sb) & 1u) << k;
        if (t < 16)
            gbm |= (unsigned long long)((gb[312] >> t) & 1u) << 39;
    }
    __syncthreads();

    int wv = t >> 6, lane = t & 63;
    float* pc = part + (size_t)(h * 4 + wv) * 5 * SPAD;

    for (int e = 0; e < EPB; ++e) {
        int s = eg * EPB + e;
        const unsigned* mrow = mask + (size_t)s * NCL + h * HHALF;
        float Z = 0.f, X = 0.f, cnt = 0.f, ng = 0.f, sg = 0.f;
        // 39 full strides = 3 batches of 13 (covers 9984)
        for (int kb = 0; kb < 3; ++kb) {
            unsigned mv[13];
            #pragma unroll
            for (int j = 0; j < 13; ++j)
                mv[j] = mrow[(kb * 13 + j) * 256 + t];
            #pragma unroll
            for (int j = 0; j < 13; ++j) {
                int k = kb * 13 + j;
                unsigned w = ELs[k * 256 + t];
                float E = __uint_as_float(w & 0xFFFF0000u);
                float L = __uint_as_float(w << 16);
                float mm = (mv[j] != 0u) ? 1.f : 0.f;
                float te = mm * E;
                Z += te;
                X = fmaf(te, L, X);
                cnt += mm;
                float mg = mm * (float)((gbm >> k) & 1ull);
                sg = fmaf(mg, L, sg);
                ng += mg;
            }
        }
        // tail clauses 9984..9999 (k = 39)
        if (t < 16) {
            unsigned mvt = mrow[9984 + t];
            unsigned w = ELs[9984 + t];
            float E = __uint_as_float(w & 0xFFFF0000u);
            float L = __uint_as_float(w << 16);
            float mm = (mvt != 0u) ? 1.f : 0.f;
            float te = mm * E;
            Z += te;
            X = fmaf(te, L, X);
            cnt += mm;
            float mg = mm * (float)((gbm >> 39) & 1ull);
            sg = fmaf(mg, L, sg);
            ng += mg;
        }
        #pragma unroll
        for (int m = 1; m < 64; m <<= 1) {
            Z   += __shfl_xor(Z, m);
            X   += __shfl_xor(X, m);
            cnt += __shfl_xor(cnt, m);
            ng  += __shfl_xor(ng, m);
            sg  += __shfl_xor(sg, m);
        }
        if (lane == 0) {
            pc[0 * SPAD + s] = Z;
            pc[1 * SPAD + s] = X;
            pc[2 * SPAD + s] = cnt;
            pc[3 * SPAD + s] = ng;
            pc[4 * SPAD + s] = sg;
        }
    }
}

// ---------- K4: final reduction (8 chunks) + epilogue ----------
__global__ __launch_bounds__(256) void k_final(const float* __restrict__ part,
                                               const float* __restrict__ logits,
                                               const float* __restrict__ times,
                                               const int* __restrict__ sel,
                                               float* __restrict__ out) {
    int s = blockIdx.x * 256 + threadIdx.x;  // 0..2047
    bool live = s < SEVN;
    float Z = 0.f, X = 0.f, cnt = 0.f, ng = 0.f, sg = 0.f;
    if (live) {
        #pragma unroll
        for (int c = 0; c < 8; ++c) {
            const float* pp = part + (size_t)c * 5 * SPAD;
            Z   += pp[0 * SPAD + s];
            X   += pp[1 * SPAD + s];
            cnt += pp[2 * SPAD + s];
            ng  += pp[3 * SPAD + s];
            sg  += pp[4 * SPAD + s];
        }
    }
    float gl = 0.f, ngs = 0.f, tl = 0.f, tv = 0.f, en = 0.f;
    if (live) {
        float L = logf(Z);
        if (ng > 0.5f) { gl = L - sg / ng; ngs = 1.f; }
        float tm = times[s];
        tl = TPM * tm * (logits[sel[s]] - L);
        tv = tm;
        en = ENTC * ((X / Z - L) / logf(cnt));
    }
    #pragma unroll
    for (int m = 1; m < 64; m <<= 1) {
        gl  += __shfl_xor(gl, m);
        ngs += __shfl_xor(ngs, m);
        tl  += __shfl_xor(tl, m);
        tv  += __shfl_xor(tv, m);
        en  += __shfl_xor(en, m);
    }
    if ((threadIdx.x & 63) == 0) {
        atomicAdd(out + 0, gl);
        atomicAdd(out + 1, ngs);
        atomicAdd(out + 2, tl);
        atomicAdd(out + 3, tv);
        atomicAdd(out + 4, en);
    }
    if (s == 0) out[5] = (float)SEVN;
}

extern "C" void kernel_launch(void* const* d_in, const int* in_sizes, int n_in,
                              void* d_out, int out_size, void* d_ws, size_t ws_size,
                              hipStream_t stream) {
    const float* fv    = (const float*)d_in[0];
    const float* W1    = (const float*)d_in[1];
    const float* b1    = (const float*)d_in[2];
    const float* W2    = (const float*)d_in[3];
    const float* b2    = (const float*)d_in[4];
    const float* key   = (const float*)d_in[5];
    const float* times = (const float*)d_in[6];
    const unsigned* mask = (const unsigned*)d_in[7];   // bool -> int32
    const int* good    = (const int*)d_in[8];          // bool -> int32
    const int* sel     = (const int*)d_in[9];
    float* out = (float*)d_out;
    char* ws = (char*)d_ws;

    float* w2k    = (float*)(ws + WS_W2K);
    float* b2k    = (float*)(ws + WS_B2K);
    float* logits = (float*)(ws + WS_LOGIT);
    unsigned* ELpk = (unsigned*)(ws + WS_ELPK);
    float* part   = (float*)(ws + WS_PART);
    unsigned short* bst = (unsigned short*)(ws + WS_BSTG);
    unsigned* gbw = (unsigned*)(ws + WS_GBW);

    hipMemsetAsync(d_out, 0, 6 * sizeof(float), stream);
    k_stream<<<NB_SB + NB_WK + NB_GB, 256, 0, stream>>>(W1, bst, W2, b2, key, good,
                                                        w2k, b2k, gbw);
    k_gemm <<<NCL / 32, 256, 0, stream>>>(fv, bst, b1, w2k, b2k, logits, ELpk);
    k_events<<<500, 256, 0, stream>>>(mask, ELpk, gbw, part);
    k_final<<<SPAD / 256, 256, 0, stream>>>(part, logits, times, sel, out);
}